// Round 15
// baseline (281.408 us; speedup 1.0000x reference)
//
#include <hip/hip_runtime.h>

#define B_ 8
#define N_ 4096
#define C_ 512
#define H_ 8

typedef _Float16 h8  __attribute__((ext_vector_type(8)));
typedef _Float16 h4v __attribute__((ext_vector_type(4)));
typedef float    f4  __attribute__((ext_vector_type(4)));

// ---- workspace layout (bytes) ----
static const size_t OFF_CT   = 0;                                  // 4 MiB u32 ct[256 jj][4096 n] = f16{cos,sin}
static const size_t OFF_XH   = (size_t)8*1024*1024;                // 32 MiB f16 [B*N][C]
static const size_t OFF_YH   = (size_t)40*1024*1024;               // 32 MiB f16 [B*N][C]
static const size_t OFF_WQH  = (size_t)72*1024*1024;               // 512 KiB f16
static const size_t OFF_WKH  = (size_t)72*1024*1024 + 512*1024;    // 512 KiB f16
static const size_t OFF_KSUM = (size_t)73*1024*1024;               // 16 KiB f32 (64K slot)
static const size_t OFF_KVG  = (size_t)73*1024*1024 + 64*1024;     // 1 MiB f32 [64bh][64d][64e]
static const size_t OFF_KVT  = (size_t)74*1024*1024 + 64*1024;     // 512 KiB f16 [64bh][64e][64d]

__device__ __forceinline__ unsigned int pack2h(float a, float b){
    union { _Float16 h[2]; unsigned int u; } x;
    x.h[0] = (_Float16)a; x.h[1] = (_Float16)b; return x.u;
}
__device__ __forceinline__ void unpack2h(unsigned int u, float& a, float& b){
    union { unsigned int u; _Float16 h[2]; } x; x.u = u;
    a = (float)x.h[0]; b = (float)x.h[1];
}

// ---- f32 -> f16 streaming converts (y, Wq, Wk) + f16 cos/sin table, one dispatch ----
__global__ __launch_bounds__(256) void k_prep(
    const float* __restrict__ y,
    const float* __restrict__ Wq, const float* __restrict__ Wk,
    _Float16* __restrict__ yh,
    _Float16* __restrict__ Wqh, _Float16* __restrict__ Wkh,
    unsigned int* __restrict__ ct)
{
    int bid = blockIdx.x;
    if (bid >= 8448){
        int jj = bid - 8448, t = threadIdx.x;
        double th = exp((double)jj * -0.035977892078031970); // ln(1e4)/256
        float thf = (float)th;
#pragma unroll
        for (int i=0;i<16;++i){
            int n = i*256 + t;
            float s, c; sincosf((float)n * thf, &s, &c);
            ct[(size_t)jj*4096 + n] = pack2h(c, s);
        }
        return;
    }
    const float* src; _Float16* dst; size_t base;
    if (bid < 8192)       { src = y;  dst = yh;  base = (size_t)bid*2048; }
    else if (bid < 8320)  { src = Wq; dst = Wqh; base = (size_t)(bid-8192)*2048; }
    else                  { src = Wk; dst = Wkh; base = (size_t)(bid-8320)*2048; }
    size_t o = base + (size_t)threadIdx.x*8;
    float4 a = *(const float4*)&src[o];
    float4 b = *(const float4*)&src[o+4];
    uint4 r; r.x = pack2h(a.x,a.y); r.y = pack2h(a.z,a.w); r.z = pack2h(b.x,b.y); r.w = pack2h(b.z,b.w);
    *(uint4*)&dst[o] = r;
}

// ---- barrier-free 1-wave GEMM (see round notes) ----
template<int IS_Q, int MI>
__global__ __launch_bounds__(64, IS_Q ? 4 : 3) void k_gemm(
    const _Float16* __restrict__ A, const _Float16* __restrict__ Wh, const float* __restrict__ bias,
    const unsigned int* __restrict__ ct,
    float* __restrict__ ksum, const float* __restrict__ ksumIn,
    float* __restrict__ kvg, const _Float16* __restrict__ kvTg,
    const _Float16* __restrict__ yh, const float* __restrict__ lw, const float* __restrict__ lb,
    float* __restrict__ outp,
    const float* __restrict__ x32, _Float16* __restrict__ xh16)
{
    __shared__ __align__(16) char smem[IS_Q ? 4608 : 16384];
    _Float16* qw = (_Float16*)smem;            // Q: [32][72] f16
    unsigned int* krU = (unsigned int*)smem;   // K: [64][32] u32, XOR-swizzled
    unsigned int* vU  = (unsigned int*)(smem + 8192);

    if constexpr (!IS_Q){
        if (blockIdx.y >= 512){
            int cb = (blockIdx.y - 512)*8 + blockIdx.x;   // 0..255
            int t = threadIdx.x;
#pragma unroll 4
            for (int it=0; it<128; ++it){
                size_t o = ((size_t)cb*128 + it)*512 + (size_t)t*8;
                float4 a = *(const float4*)&x32[o];
                float4 b = *(const float4*)&x32[o+4];
                uint4 r; r.x = pack2h(a.x,a.y); r.y = pack2h(a.z,a.w);
                r.z = pack2h(b.x,b.y); r.w = pack2h(b.z,b.w);
                *(uint4*)&xh16[o] = r;
            }
            return;
        }
    }

    const int t = threadIdx.x;            // lane
    const int lrow = t & 15, lg = t >> 4;
    const int d_lin = blockIdx.x + (blockIdx.y << 3);
    const int xcd = d_lin & 7, s = d_lin >> 3;
    const int col0 = (s & 7) * 64;        // head window
    const int row0 = IS_Q ? (xcd*128 + (s >> 3))*32 : (xcd*64 + (s >> 3))*64;
    const int b = row0 >> 12;
    const int bh = b*H_ + (col0 >> 6);

    f4 acc[MI][4] = {};
    const _Float16* pa = A  + ((size_t)(row0 + lrow))*C_ + lg*8;
    const _Float16* pb = Wh + ((size_t)(col0 + lrow))*C_ + lg*8;
#pragma unroll
    for (int kk=0; kk<16; ++kk){
        h8 af[MI], bf[4];
#pragma unroll
        for (int mi=0; mi<MI; ++mi) af[mi] = *(const h8*)(pa + (size_t)mi*16*C_ + kk*32);
#pragma unroll
        for (int ni=0; ni<4; ++ni)  bf[ni] = *(const h8*)(pb + (size_t)ni*16*C_ + kk*32);
#pragma unroll
        for (int mi=0; mi<MI; ++mi)
#pragma unroll
            for (int ni=0; ni<4; ++ni)
                acc[mi][ni] = __builtin_amdgcn_mfma_f32_16x16x32_f16(af[mi], bf[ni], acc[mi][ni], 0,0,0);
    }

    float bcol[4], km[4];
#pragma unroll
    for (int ni=0; ni<4; ++ni){
        int c = col0 + ni*16 + lrow;
        bcol[ni] = bias[c];
        km[ni] = IS_Q ? ksumIn[b*C_ + c] * (1.0f/4096.0f) : 0.0f;
    }
    float colsum[4] = {0.f,0.f,0.f,0.f};
    float zr[MI][4];

#pragma unroll
    for (int mi=0; mi<MI; ++mi){
        float qv[4][4];
#pragma unroll
        for (int ni=0; ni<4; ++ni)
#pragma unroll
            for (int r=0; r<4; ++r){
                float v = acc[mi][ni][r] + bcol[ni];
                qv[ni][r] = v > 0.f ? v + 1.f : __expf(v);   // elu+1
            }
        if constexpr (IS_Q){
#pragma unroll
            for (int r=0; r<4; ++r){
                float p = qv[0][r]*km[0] + qv[1][r]*km[1] + qv[2][r]*km[2] + qv[3][r]*km[3];
                p += __shfl_xor(p, 1); p += __shfl_xor(p, 2);
                p += __shfl_xor(p, 4); p += __shfl_xor(p, 8);
                zr[mi][r] = 1.0f / (p + 1e-6f);
            }
        } else {
#pragma unroll
            for (int ni=0; ni<4; ++ni)
                colsum[ni] += qv[ni][0]+qv[ni][1]+qv[ni][2]+qv[ni][3];
        }
        const int n0 = (row0 & (N_-1)) + mi*16 + lg*4;
#pragma unroll
        for (int ni=0; ni<4; ++ni){
            int c = col0 + ni*16 + lrow;
            int jj = c >> 1;
            uint4 tu = *(const uint4*)&ct[(size_t)jj*4096 + n0];
            float cs4[4], sn4[4];
            unpack2h(tu.x, cs4[0], sn4[0]);
            unpack2h(tu.y, cs4[1], sn4[1]);
            unpack2h(tu.z, cs4[2], sn4[2]);
            unpack2h(tu.w, cs4[3], sn4[3]);
            float rv[4];
#pragma unroll
            for (int r=0; r<4; ++r){
                float val = qv[ni][r];
                float par = __shfl_xor(val, 1);
                rv[r] = (t & 1) ? fmaf(sn4[r], par, cs4[r]*val) : fmaf(cs4[r], val, -sn4[r]*par);
            }
            if constexpr (IS_Q){
#pragma unroll
                for (int r=0; r<4; ++r){
                    float prv = __shfl_xor(rv[r], 1);
                    if (!(t & 1))
                        *(unsigned int*)&qw[(mi*16 + lg*4 + r)*72 + (ni*16 + lrow)] = pack2h(rv[r], prv);
                }
            } else {
                int dd = ni*16 + lrow;
                int n2 = mi*8 + lg*2;
                unsigned int* p = &krU[dd*32 + (n2 ^ ((dd & 7) << 2))];
                uint2 pr; pr.x = pack2h(rv[0], rv[1]); pr.y = pack2h(rv[2], rv[3]);
                *(uint2*)p = pr;
            }
        }
    }

    if constexpr (!IS_Q){
#pragma unroll
        for (int ni=0; ni<4; ++ni){
            float ss = colsum[ni];
            ss += __shfl_xor(ss, 16); ss += __shfl_xor(ss, 32);
            if (t < 16) atomicAdd(&ksum[b*C_ + col0 + ni*16 + t], ss);
        }
#pragma unroll
        for (int it=0; it<8; ++it){
            int n2g = it*4 + lg;           // 0..31
            int e4 = lrow*4;
            uint2 r0 = *(const uint2*)&yh[(size_t)(row0 + 2*n2g)*C_ + col0 + e4];
            uint2 r1 = *(const uint2*)&yh[(size_t)(row0 + 2*n2g + 1)*C_ + col0 + e4];
            unsigned int v0 = (r0.x & 0xffffu) | (r1.x << 16);
            unsigned int v1 = (r0.x >> 16)     | (r1.x & 0xffff0000u);
            unsigned int v2 = (r0.y & 0xffffu) | (r1.y << 16);
            unsigned int v3 = (r0.y >> 16)     | (r1.y & 0xffff0000u);
            vU[(e4+0)*32 + (n2g ^ (((e4+0) & 7) << 2))] = v0;
            vU[(e4+1)*32 + (n2g ^ (((e4+1) & 7) << 2))] = v1;
            vU[(e4+2)*32 + (n2g ^ (((e4+2) & 7) << 2))] = v2;
            vU[(e4+3)*32 + (n2g ^ (((e4+3) & 7) << 2))] = v3;
        }
        __syncthreads();
        f4 acc2[4][4] = {};
#pragma unroll
        for (int ks=0; ks<2; ++ks){
            h8 a2[4], b2[4];
#pragma unroll
            for (int mi2=0; mi2<4; ++mi2){
                int dd = mi2*16 + lrow;
                int c4 = (ks*16 + lg*4) ^ ((dd & 7) << 2);
                a2[mi2] = *(const h8*)&krU[dd*32 + c4];
            }
#pragma unroll
            for (int ni2=0; ni2<4; ++ni2){
                int e = ni2*16 + lrow;
                int c4 = (ks*16 + lg*4) ^ ((e & 7) << 2);
                b2[ni2] = *(const h8*)&vU[e*32 + c4];
            }
#pragma unroll
            for (int mi2=0; mi2<4; ++mi2)
#pragma unroll
                for (int ni2=0; ni2<4; ++ni2)
                    acc2[mi2][ni2] = __builtin_amdgcn_mfma_f32_16x16x32_f16(a2[mi2], b2[ni2], acc2[mi2][ni2], 0,0,0);
        }
#pragma unroll
        for (int mi2=0; mi2<4; ++mi2)
#pragma unroll
            for (int ni2=0; ni2<4; ++ni2)
#pragma unroll
                for (int rr=0; rr<4; ++rr){
                    int dd = mi2*16 + lg*4 + rr;
                    int e = ni2*16 + lrow;
                    atomicAdd(&kvg[(size_t)bh*4096 + dd*64 + e], acc2[mi2][ni2][rr] * (1.0f/4096.0f));
                }
    } else {
        h8 kv0[4], kv1[4];
#pragma unroll
        for (int ni2=0; ni2<4; ++ni2){
            int e = ni2*16 + lrow;
            kv0[ni2] = *(const h8*)&kvTg[(size_t)bh*4096 + e*64 + lg*8];
            kv1[ni2] = *(const h8*)&kvTg[(size_t)bh*4096 + e*64 + 32 + lg*8];
        }
        __syncthreads();
        f4 acc2[2][4] = {};
#pragma unroll
        for (int mi2=0; mi2<2; ++mi2){
            h8 a0 = *(const h8*)&qw[(mi2*16 + lrow)*72 + 0*32 + lg*8];
            h8 a1 = *(const h8*)&qw[(mi2*16 + lrow)*72 + 1*32 + lg*8];
#pragma unroll
            for (int ni2=0; ni2<4; ++ni2){
                acc2[mi2][ni2] = __builtin_amdgcn_mfma_f32_16x16x32_f16(a0, kv0[ni2], acc2[mi2][ni2], 0,0,0);
                acc2[mi2][ni2] = __builtin_amdgcn_mfma_f32_16x16x32_f16(a1, kv1[ni2], acc2[mi2][ni2], 0,0,0);
            }
        }
#pragma unroll
        for (int mi2=0; mi2<2; ++mi2){
#pragma unroll
            for (int r=0; r<4; ++r){
                float z = zr[mi2][r];
#pragma unroll
                for (int ni2=0; ni2<4; ++ni2){
                    float val = acc2[mi2][ni2][r] * z;
                    float pv = __shfl_xor(val, 1);
                    if (!(t & 1))
                        *(unsigned int*)&qw[(mi2*16 + lg*4 + r)*72 + (ni2*16 + lrow)] = pack2h(val, pv);
                }
            }
        }
        __syncthreads();
        const int e4 = (t & 15)*4;
        float w0[4], w1[4], w2[4], wb[4];
#pragma unroll
        for (int j=0;j<4;++j){
            int cc = col0 + e4 + j;
            w0[j]=lw[cc*3+0]; w1[j]=lw[cc*3+1]; w2[j]=lw[cc*3+2]; wb[j]=lb[cc];
        }
#pragma unroll
        for (int i=0;i<8;++i){
            int rl = i*4 + lg;
            int grow = row0 + rl;
            int nloc = grow & (N_-1);
            h4v a = *(const h4v*)&qw[rl*72 + e4];
            const _Float16* yp = yh + (size_t)grow*C_ + col0 + e4;
            h4v y1 = *(const h4v*)yp;
            float s0 = fmaf((float)y1[0], w1[0], wb[0]);
            float s1 = fmaf((float)y1[1], w1[1], wb[1]);
            float s2 = fmaf((float)y1[2], w1[2], wb[2]);
            float s3 = fmaf((float)y1[3], w1[3], wb[3]);
            if (nloc > 0){
                h4v y0 = *(const h4v*)(yp - C_);
                s0 = fmaf((float)y0[0], w0[0], s0); s1 = fmaf((float)y0[1], w0[1], s1);
                s2 = fmaf((float)y0[2], w0[2], s2); s3 = fmaf((float)y0[3], w0[3], s3);
            }
            if (nloc < N_-1){
                h4v y2 = *(const h4v*)(yp + C_);
                s0 = fmaf((float)y2[0], w2[0], s0); s1 = fmaf((float)y2[1], w2[1], s1);
                s2 = fmaf((float)y2[2], w2[2], s2); s3 = fmaf((float)y2[3], w2[3], s3);
            }
            float4 o;
            o.x = (float)a[0] + s0; o.y = (float)a[1] + s1;
            o.z = (float)a[2] + s2; o.w = (float)a[3] + s3;
            *(float4*)&outp[(size_t)grow*C_ + col0 + e4] = o;
        }
    }
}

// ---- kvg f32 [bh][d][e] -> kvTg f16 [bh][e][d] ----
__global__ __launch_bounds__(256) void k_kvmerge(const float* __restrict__ kvg, _Float16* __restrict__ kvTg){
    int bh = blockIdx.x, t = threadIdx.x;
    const float* src = kvg + (size_t)bh*4096;
    _Float16* dst = kvTg + (size_t)bh*4096;
#pragma unroll
    for (int i=0;i<4;++i){
        int q = i*256 + t;
        int e2 = q & 31, d2 = q >> 5;
        float2 a0 = *(const float2*)&src[(2*d2)*64 + 2*e2];
        float2 a1 = *(const float2*)&src[(2*d2+1)*64 + 2*e2];
        *(unsigned int*)&dst[(2*e2)*64 + 2*d2]   = pack2h(a0.x, a1.x);
        *(unsigned int*)&dst[(2*e2+1)*64 + 2*d2] = pack2h(a0.y, a1.y);
    }
}

extern "C" void kernel_launch(void* const* d_in, const int* in_sizes, int n_in,
                              void* d_out, int out_size, void* d_ws, size_t ws_size,
                              hipStream_t stream)
{
    (void)in_sizes; (void)n_in; (void)out_size; (void)ws_size;
    const float* x  = (const float*)d_in[0];
    const float* y  = (const float*)d_in[1];
    const float* Wq = (const float*)d_in[2];
    const float* bq = (const float*)d_in[3];
    const float* Wk = (const float*)d_in[4];
    const float* bk = (const float*)d_in[5];
    const float* lw = (const float*)d_in[6];
    const float* lb = (const float*)d_in[7];

    char* ws = (char*)d_ws;
    unsigned int* ct = (unsigned int*)(ws + OFF_CT);
    _Float16* xh   = (_Float16*)(ws + OFF_XH);
    _Float16* yh   = (_Float16*)(ws + OFF_YH);
    _Float16* Wqh  = (_Float16*)(ws + OFF_WQH);
    _Float16* Wkh  = (_Float16*)(ws + OFF_WKH);
    float*    ksum = (float*)(ws + OFF_KSUM);
    float*    kvg  = (float*)(ws + OFF_KVG);
    _Float16* kvTg = (_Float16*)(ws + OFF_KVT);
    float*    out  = (float*)d_out;

    hipMemsetAsync(ws + OFF_KSUM, 0, 64*1024 + 1024*1024, stream);   // ksum + kvg
    k_prep<<<dim3(8704), dim3(256), 0, stream>>>(y, Wq, Wk, yh, Wqh, Wkh, ct);
    k_gemm<0,4><<<dim3(8, 544), dim3(64), 0, stream>>>(yh, Wkh, bk, ct,
        ksum, nullptr, kvg, nullptr, yh, nullptr, nullptr, nullptr, x, xh);
    k_kvmerge<<<dim3(64), dim3(256), 0, stream>>>(kvg, kvTg);
    k_gemm<1,2><<<dim3(8, 1024), dim3(64), 0, stream>>>(xh, Wqh, bq, ct,
        nullptr, ksum, nullptr, kvTg, yh, lw, lb, out, nullptr, nullptr);
}

// Round 16
// 183.726 us; speedup vs baseline: 1.5317x; 1.5317x over previous
//
#include <hip/hip_runtime.h>

#define B_ 8
#define N_ 4096
#define C_ 512
#define H_ 8

typedef _Float16 h8  __attribute__((ext_vector_type(8)));
typedef _Float16 h4v __attribute__((ext_vector_type(4)));
typedef float    f4  __attribute__((ext_vector_type(4)));

// ---- workspace layout (bytes) ----
static const size_t OFF_CT   = 0;                                  // 4 MiB u32 ct[256 jj][4096 n] = f16{cos,sin}
static const size_t OFF_XH   = (size_t)8*1024*1024;                // 32 MiB f16 [B*N][C]
static const size_t OFF_YH   = (size_t)40*1024*1024;               // 32 MiB f16 [B*N][C]
static const size_t OFF_WQH  = (size_t)72*1024*1024;               // 512 KiB f16
static const size_t OFF_WKH  = (size_t)72*1024*1024 + 512*1024;    // 512 KiB f16
static const size_t OFF_KSUM = (size_t)73*1024*1024;               // 16 KiB f32 (64K slot)
static const size_t OFF_KVG  = (size_t)73*1024*1024 + 64*1024;     // 1 MiB f32 [64bh][64d][64e]
static const size_t OFF_KVT  = (size_t)74*1024*1024 + 64*1024;     // 512 KiB f16 [64bh][64e][64d]

__device__ __forceinline__ unsigned int pack2h(float a, float b){
    union { _Float16 h[2]; unsigned int u; } x;
    x.h[0] = (_Float16)a; x.h[1] = (_Float16)b; return x.u;
}
__device__ __forceinline__ void unpack2h(unsigned int u, float& a, float& b){
    union { unsigned int u; _Float16 h[2]; } x; x.u = u;
    a = (float)x.h[0]; b = (float)x.h[1];
}

// ---- f32 -> f16 streaming converts (y, Wq, Wk) + f16 cos/sin table, one dispatch ----
__global__ __launch_bounds__(256) void k_prep(
    const float* __restrict__ y,
    const float* __restrict__ Wq, const float* __restrict__ Wk,
    _Float16* __restrict__ yh,
    _Float16* __restrict__ Wqh, _Float16* __restrict__ Wkh,
    unsigned int* __restrict__ ct)
{
    int bid = blockIdx.x;
    if (bid >= 8448){
        int jj = bid - 8448, t = threadIdx.x;
        double th = exp((double)jj * -0.035977892078031970); // ln(1e4)/256
        float thf = (float)th;
#pragma unroll
        for (int i=0;i<16;++i){
            int n = i*256 + t;
            float s, c; sincosf((float)n * thf, &s, &c);
            ct[(size_t)jj*4096 + n] = pack2h(c, s);
        }
        return;
    }
    const float* src; _Float16* dst; size_t base;
    if (bid < 8192)       { src = y;  dst = yh;  base = (size_t)bid*2048; }
    else if (bid < 8320)  { src = Wq; dst = Wqh; base = (size_t)(bid-8192)*2048; }
    else                  { src = Wk; dst = Wkh; base = (size_t)(bid-8320)*2048; }
    size_t o = base + (size_t)threadIdx.x*8;
    float4 a = *(const float4*)&src[o];
    float4 b = *(const float4*)&src[o+4];
    uint4 r; r.x = pack2h(a.x,a.y); r.y = pack2h(a.z,a.w); r.z = pack2h(b.x,b.y); r.w = pack2h(b.z,b.w);
    *(uint4*)&dst[o] = r;
}

// ---- stage f16 tiles via global_load_lds; linear dest, source pre-swizzled ----
__device__ __forceinline__ void stage_a64(const _Float16* __restrict__ g, _Float16* lds, int t){
    int r = t >> 2;
    int j = (t & 3) ^ ((r ^ (r >> 2)) & 3);
    __builtin_amdgcn_global_load_lds(
        (const __attribute__((address_space(1))) void*)(g + (size_t)r*C_ + j*8),
        (__attribute__((address_space(3))) void*)(lds + (size_t)(t & 192)*8),
        16, 0, 0);
}
__device__ __forceinline__ void stage_b128(const _Float16* __restrict__ g, _Float16* lds, int t){
#pragma unroll
    for (int i=0;i<2;++i){
        int u = i*256 + t;
        int r = u >> 2;
        int j = (u & 3) ^ ((r ^ (r >> 2)) & 3);
        __builtin_amdgcn_global_load_lds(
            (const __attribute__((address_space(1))) void*)(g + (size_t)r*C_ + j*8),
            (__attribute__((address_space(3))) void*)(lds + (size_t)(i*256 + (t & 192))*8),
            16, 0, 0);
    }
}

// ---- fused GEMM, BM=64 x BN=128; XCD-aware bijective swizzle ----
// IS_Q=0: grid (4,576): by<64 = 256 x->f16 conversion blocks placed FIRST so their streaming
//         overlaps the gemm ramp (in-order dispatch; xh consumed only by the NEXT dispatch);
//         by>=64 = k path (ksum + fused kv partial atomics).
// IS_Q=1: grid (4,512): q path -> fused z, qr@kv (kvTg from L2), lepe, coalesced out.
template<int IS_Q>
__global__ __launch_bounds__(256, 4) void k_gemm(
    const _Float16* __restrict__ A, const _Float16* __restrict__ Wh, const float* __restrict__ bias,
    const unsigned int* __restrict__ ct,
    float* __restrict__ ksum, const float* __restrict__ ksumIn,
    float* __restrict__ kvg, const _Float16* __restrict__ kvTg,
    const _Float16* __restrict__ yh, const float* __restrict__ lw, const float* __restrict__ lb,
    float* __restrict__ outp,
    const float* __restrict__ x32, _Float16* __restrict__ xh16)
{
    // main: A slots 3x4096 @0, B slots 3x8192 @12288 = 36864
    // K epilogue: krs u32 [2 head][64 d][32 n2] @0 (16K), vs same @16384 (16K)
    // Q epilogue: qrs 4 x [32][72] f16 @0 (18432)
    __shared__ __align__(16) char smem[36864];
    _Float16* qrs = (_Float16*)smem;
    unsigned int* krsU = (unsigned int*)smem;
    unsigned int* vsU  = (unsigned int*)(smem + 16384);

    if constexpr (!IS_Q){
        if (blockIdx.y < 64){
            // x -> f16 streaming conversion (front of grid: overlaps gemm ramp-up)
            int cb = blockIdx.y*4 + blockIdx.x;   // 0..255
#pragma unroll 4
            for (int it=0; it<32; ++it){
                size_t o = ((size_t)(cb*32 + it))*2048 + (size_t)threadIdx.x*8;
                float4 a = *(const float4*)&x32[o];
                float4 b = *(const float4*)&x32[o+4];
                uint4 r; r.x = pack2h(a.x,a.y); r.y = pack2h(a.z,a.w);
                r.z = pack2h(b.x,b.y); r.w = pack2h(b.z,b.w);
                *(uint4*)&xh16[o] = r;
            }
            return;
        }
    }

    const int t = threadIdx.x;
    const int lane = t & 63;
    const int w = t >> 6;
    const int wm = w >> 1, wn = w & 1;
    // XCD-aware bijective remap (2048 = 8 XCD x 256); batch b pinned to XCD b
    const int byg = IS_Q ? blockIdx.y : (blockIdx.y - 64);
    const int d_lin = blockIdx.x + (byg << 2);
    const int xcd = d_lin & 7;
    const int sq  = d_lin >> 3;
    const int col0 = (sq & 3) * 128;
    const int row0 = (xcd * 64 + (sq >> 2)) * 64;
    const int lrow = lane & 15, lg = lane >> 4;
    const int b = row0 >> 12;

    f4 acc[2][4] = {};
    const _Float16* Ab = A  + (size_t)row0*C_;
    const _Float16* Bb = Wh + (size_t)col0*C_;
    stage_a64 (Ab,      (_Float16*)(smem),               t);
    stage_b128(Bb,      (_Float16*)(smem + 12288),       t);
    stage_a64 (Ab + 32, (_Float16*)(smem + 4096),        t);
    stage_b128(Bb + 32, (_Float16*)(smem + 12288 + 8192),t);

    const int sw = (lrow ^ (lrow >> 2)) & 3;
    const int cK = (lg ^ sw) * 8;

#pragma unroll
    for (int kk=0; kk<16; ++kk){
        if (kk < 15) asm volatile("s_waitcnt vmcnt(3)" ::: "memory");
        else         asm volatile("s_waitcnt vmcnt(0)" ::: "memory");
        __builtin_amdgcn_s_barrier();
        if (kk < 14){
            const int ss = (kk+2)%3;
            stage_a64 (Ab + (kk+2)*32, (_Float16*)(smem + ss*4096),         t);
            stage_b128(Bb + (kk+2)*32, (_Float16*)(smem + 12288 + ss*8192), t);
        }
        const int sc = kk%3;
        const _Float16* As = (const _Float16*)(smem + sc*4096);
        const _Float16* Bs = (const _Float16*)(smem + 12288 + sc*8192);
        h8 af[2], bf[4];
#pragma unroll
        for (int mi=0; mi<2; ++mi) af[mi] = *(const h8*)&As[(wm*32 + mi*16 + lrow)*32 + cK];
#pragma unroll
        for (int ni=0; ni<4; ++ni) bf[ni] = *(const h8*)&Bs[(wn*64 + ni*16 + lrow)*32 + cK];
#pragma unroll
        for (int mi=0; mi<2; ++mi)
#pragma unroll
            for (int ni=0; ni<4; ++ni)
                acc[mi][ni] = __builtin_amdgcn_mfma_f32_16x16x32_f16(af[mi], bf[ni], acc[mi][ni], 0,0,0);
    }
    __syncthreads();   // all LDS reads done; slots reusable

    // ---- epilogue ----
    const int hcol0 = col0 + wn*64;
    float bcol[4], km[4];
#pragma unroll
    for (int ni=0; ni<4; ++ni){
        int c = hcol0 + ni*16 + lrow;
        bcol[ni] = bias[c];
        km[ni] = IS_Q ? ksumIn[b*C_ + c] * (1.0f/4096.0f) : 0.0f;
    }
    float colsum[4] = {0.f,0.f,0.f,0.f};
    float zr[2][4];
    _Float16* qw = qrs + w*2304;   // (Q) wave-local [32][72]

#pragma unroll
    for (int mi=0; mi<2; ++mi){
        float qv[4][4];
#pragma unroll
        for (int ni=0; ni<4; ++ni)
#pragma unroll
            for (int r=0; r<4; ++r){
                float v = acc[mi][ni][r] + bcol[ni];
                qv[ni][r] = v > 0.f ? v + 1.f : __expf(v);   // elu+1
            }
        if constexpr (IS_Q){
#pragma unroll
            for (int r=0; r<4; ++r){
                float p = qv[0][r]*km[0] + qv[1][r]*km[1] + qv[2][r]*km[2] + qv[3][r]*km[3];
                p += __shfl_xor(p, 1); p += __shfl_xor(p, 2);
                p += __shfl_xor(p, 4); p += __shfl_xor(p, 8);
                zr[mi][r] = 1.0f / (p + 1e-6f);
            }
        } else {
#pragma unroll
            for (int ni=0; ni<4; ++ni)
                colsum[ni] += qv[ni][0]+qv[ni][1]+qv[ni][2]+qv[ni][3];
        }
        // rope (f16-packed transposed table: one uint4 per (mi,ni))
        const int n0 = (row0 & (N_-1)) + wm*32 + mi*16 + lg*4;
#pragma unroll
        for (int ni=0; ni<4; ++ni){
            int c = hcol0 + ni*16 + lrow;
            int jj = c >> 1;
            uint4 tu = *(const uint4*)&ct[(size_t)jj*4096 + n0];
            float cs4[4], sn4[4];
            unpack2h(tu.x, cs4[0], sn4[0]);
            unpack2h(tu.y, cs4[1], sn4[1]);
            unpack2h(tu.z, cs4[2], sn4[2]);
            unpack2h(tu.w, cs4[3], sn4[3]);
            float rv[4];
#pragma unroll
            for (int r=0; r<4; ++r){
                float val = qv[ni][r];
                float par = __shfl_xor(val, 1);
                rv[r] = (lane & 1) ? fmaf(sn4[r], par, cs4[r]*val) : fmaf(cs4[r], val, -sn4[r]*par);
            }
            if constexpr (IS_Q){
#pragma unroll
                for (int r=0; r<4; ++r){
                    float prv = __shfl_xor(rv[r], 1);
                    if (!(lane & 1))
                        *(unsigned int*)&qw[(mi*16 + lg*4 + r)*72 + (ni*16 + lrow)] = pack2h(rv[r], prv);
                }
            } else {
                // krs u32 [d][32 n2], phys col = n2 ^ ((d&7)<<2); all lanes write uint2
                int d = ni*16 + lrow;
                int n2 = wm*16 + mi*8 + lg*2;
                unsigned int* p = &krsU[wn*2048 + d*32 + (n2 ^ ((d & 7) << 2))];
                uint2 pr; pr.x = pack2h(rv[0], rv[1]); pr.y = pack2h(rv[2], rv[3]);
                *(uint2*)p = pr;
            }
        }
    }

    if constexpr (!IS_Q){
        // ksum column sums
#pragma unroll
        for (int ni=0; ni<4; ++ni){
            float s = colsum[ni];
            s += __shfl_xor(s, 16); s += __shfl_xor(s, 32);
            if (lane < 16) atomicAdd(&ksum[b*C_ + hcol0 + ni*16 + lane], s);
        }
        // stage v = yh block rows into vs [e][n] transposed, same swizzle
        {
            const int grp = lane >> 4, li = lane & 15;
#pragma unroll
            for (int it=0; it<8; ++it){
                int g = it*4 + w;              // 0..31
                int hl = g >> 4, q = g & 15;   // head, 4-row quad
                int row = q*4 + grp;
                uint2 mine = *(const uint2*)&yh[(size_t)(row0 + row)*C_ + col0 + hl*64 + li*4];
                uint2 oth; oth.x = __shfl_xor(mine.x, 16); oth.y = __shfl_xor(mine.y, 16);
                if (!(grp & 1)){
                    int n2 = row >> 1;
#pragma unroll
                    for (int e=0; e<4; ++e){
                        int ea = li*4 + e;
                        unsigned int mf = ((e<2 ? mine.x : mine.y) >> ((e&1)*16)) & 0xffffu;
                        unsigned int of = ((e<2 ? oth.x  : oth.y ) >> ((e&1)*16)) & 0xffffu;
                        vsU[hl*2048 + ea*32 + (n2 ^ ((ea & 7) << 2))] = mf | (of << 16);
                    }
                }
            }
        }
        __syncthreads();
        // kv partial: wave (wm,wn): head wn, d-half wm. kv[d][e] = sum_n kr[n,d] v[n,e]
        f4 acc2[2][4] = {};
        const unsigned int* krsW = krsU + wn*2048;
        const unsigned int* vsW  = vsU  + wn*2048;
#pragma unroll
        for (int ks=0; ks<2; ++ks){
            h8 a2[2], b2[4];
#pragma unroll
            for (int mi2=0; mi2<2; ++mi2){
                int d = wm*32 + mi2*16 + lrow;
                int c4 = (ks*16 + lg*4) ^ ((d & 7) << 2);
                a2[mi2] = *(const h8*)&krsW[d*32 + c4];
            }
#pragma unroll
            for (int ni2=0; ni2<4; ++ni2){
                int e = ni2*16 + lrow;
                int c4 = (ks*16 + lg*4) ^ ((e & 7) << 2);
                b2[ni2] = *(const h8*)&vsW[e*32 + c4];
            }
#pragma unroll
            for (int mi2=0; mi2<2; ++mi2)
#pragma unroll
                for (int ni2=0; ni2<4; ++ni2)
                    acc2[mi2][ni2] = __builtin_amdgcn_mfma_f32_16x16x32_f16(a2[mi2], b2[ni2], acc2[mi2][ni2], 0,0,0);
        }
        const int bh = b*H_ + (col0 >> 6) + wn;
#pragma unroll
        for (int mi2=0; mi2<2; ++mi2)
#pragma unroll
            for (int ni2=0; ni2<4; ++ni2)
#pragma unroll
                for (int rr=0; rr<4; ++rr){
                    int d = wm*32 + mi2*16 + lg*4 + rr;
                    int e = ni2*16 + lrow;
                    atomicAdd(&kvg[(size_t)bh*4096 + d*64 + e], acc2[mi2][ni2][rr] * (1.0f/4096.0f));
                }
    } else {
        // kv fragments straight from L2 (kvTg is 512 KiB, resident)
        const int bhh = b*H_ + (col0 >> 6) + wn;
        h8 kv0[4], kv1[4];
#pragma unroll
        for (int ni2=0; ni2<4; ++ni2){
            int e = ni2*16 + lrow;
            kv0[ni2] = *(const h8*)&kvTg[(size_t)bhh*4096 + e*64 + lg*8];
            kv1[ni2] = *(const h8*)&kvTg[(size_t)bhh*4096 + e*64 + 32 + lg*8];
        }
        __syncthreads();   // qrs written by all waves
        f4 acc2[2][4] = {};
#pragma unroll
        for (int mi2=0; mi2<2; ++mi2){
            h8 a0 = *(const h8*)&qw[(mi2*16 + lrow)*72 + 0*32 + lg*8];
            h8 a1 = *(const h8*)&qw[(mi2*16 + lrow)*72 + 1*32 + lg*8];
#pragma unroll
            for (int ni2=0; ni2<4; ++ni2){
                acc2[mi2][ni2] = __builtin_amdgcn_mfma_f32_16x16x32_f16(a0, kv0[ni2], acc2[mi2][ni2], 0,0,0);
                acc2[mi2][ni2] = __builtin_amdgcn_mfma_f32_16x16x32_f16(a1, kv1[ni2], acc2[mi2][ni2], 0,0,0);
            }
        }
        // z-scale, write back f16 into own qw tile
#pragma unroll
        for (int mi2=0; mi2<2; ++mi2){
#pragma unroll
            for (int r=0; r<4; ++r){
                float z = zr[mi2][r];
#pragma unroll
                for (int ni2=0; ni2<4; ++ni2){
                    float val = acc2[mi2][ni2][r] * z;
                    float pv = __shfl_xor(val, 1);
                    if (!(lane & 1))
                        *(unsigned int*)&qw[(mi2*16 + lg*4 + r)*72 + (ni2*16 + lrow)] = pack2h(val, pv);
                }
            }
        }
        __syncthreads();
        // row-major remap: lepe (reads yh) + out, fully coalesced
        const int cg = t & 31;
        const int c4p = cg * 4;
        const int hl = c4p >> 6;
        const int e0 = c4p & 63;
        float w0[4], w1[4], w2[4], wb[4];
#pragma unroll
        for (int j=0;j<4;++j){
            int cc = col0 + c4p + j;
            w0[j]=lw[cc*3+0]; w1[j]=lw[cc*3+1]; w2[j]=lw[cc*3+2]; wb[j]=lb[cc];
        }
#pragma unroll
        for (int i=0;i<8;++i){
            int rl = (t >> 5) + i*8;
            int grow = row0 + rl;
            int nloc = grow & (N_-1);
            int wreg = ((rl >> 5) << 1) + hl;
            h4v a = *(const h4v*)&qrs[wreg*2304 + (rl & 31)*72 + e0];
            const _Float16* yp = yh + (size_t)grow*C_ + col0 + c4p;
            h4v y1 = *(const h4v*)yp;
            float s0 = fmaf((float)y1[0], w1[0], wb[0]);
            float s1 = fmaf((float)y1[1], w1[1], wb[1]);
            float s2 = fmaf((float)y1[2], w1[2], wb[2]);
            float s3 = fmaf((float)y1[3], w1[3], wb[3]);
            if (nloc > 0){
                h4v y0 = *(const h4v*)(yp - C_);
                s0 = fmaf((float)y0[0], w0[0], s0); s1 = fmaf((float)y0[1], w0[1], s1);
                s2 = fmaf((float)y0[2], w0[2], s2); s3 = fmaf((float)y0[3], w0[3], s3);
            }
            if (nloc < N_-1){
                h4v y2 = *(const h4v*)(yp + C_);
                s0 = fmaf((float)y2[0], w2[0], s0); s1 = fmaf((float)y2[1], w2[1], s1);
                s2 = fmaf((float)y2[2], w2[2], s2); s3 = fmaf((float)y2[3], w2[3], s3);
            }
            float4 o;
            o.x = (float)a[0] + s0; o.y = (float)a[1] + s1;
            o.z = (float)a[2] + s2; o.w = (float)a[3] + s3;
            *(float4*)&outp[(size_t)grow*C_ + col0 + c4p] = o;
        }
    }
}

// ---- kvg f32 [bh][d][e] -> kvTg f16 [bh][e][d] ----
__global__ __launch_bounds__(256) void k_kvmerge(const float* __restrict__ kvg, _Float16* __restrict__ kvTg){
    int bh = blockIdx.x, t = threadIdx.x;
    const float* src = kvg + (size_t)bh*4096;
    _Float16* dst = kvTg + (size_t)bh*4096;
#pragma unroll
    for (int i=0;i<4;++i){
        int q = i*256 + t;
        int e2 = q & 31, d2 = q >> 5;
        float2 a0 = *(const float2*)&src[(2*d2)*64 + 2*e2];
        float2 a1 = *(const float2*)&src[(2*d2+1)*64 + 2*e2];
        *(unsigned int*)&dst[(2*e2)*64 + 2*d2]   = pack2h(a0.x, a1.x);
        *(unsigned int*)&dst[(2*e2+1)*64 + 2*d2] = pack2h(a0.y, a1.y);
    }
}

extern "C" void kernel_launch(void* const* d_in, const int* in_sizes, int n_in,
                              void* d_out, int out_size, void* d_ws, size_t ws_size,
                              hipStream_t stream)
{
    (void)in_sizes; (void)n_in; (void)out_size; (void)ws_size;
    const float* x  = (const float*)d_in[0];
    const float* y  = (const float*)d_in[1];
    const float* Wq = (const float*)d_in[2];
    const float* bq = (const float*)d_in[3];
    const float* Wk = (const float*)d_in[4];
    const float* bk = (const float*)d_in[5];
    const float* lw = (const float*)d_in[6];
    const float* lb = (const float*)d_in[7];

    char* ws = (char*)d_ws;
    unsigned int* ct = (unsigned int*)(ws + OFF_CT);
    _Float16* xh   = (_Float16*)(ws + OFF_XH);
    _Float16* yh   = (_Float16*)(ws + OFF_YH);
    _Float16* Wqh  = (_Float16*)(ws + OFF_WQH);
    _Float16* Wkh  = (_Float16*)(ws + OFF_WKH);
    float*    ksum = (float*)(ws + OFF_KSUM);
    float*    kvg  = (float*)(ws + OFF_KVG);
    _Float16* kvTg = (_Float16*)(ws + OFF_KVT);
    float*    out  = (float*)d_out;

    hipMemsetAsync(ws + OFF_KSUM, 0, 64*1024 + 1024*1024, stream);   // ksum + kvg
    k_prep<<<dim3(8704), dim3(256), 0, stream>>>(y, Wq, Wk, yh, Wqh, Wkh, ct);
    k_gemm<0><<<dim3(4, 576), dim3(256), 0, stream>>>(yh, Wkh, bk, ct,
        ksum, nullptr, kvg, nullptr, yh, nullptr, nullptr, nullptr, x, xh);
    k_kvmerge<<<dim3(64), dim3(256), 0, stream>>>(kvg, kvTg);
    k_gemm<1><<<dim3(4, 512), dim3(256), 0, stream>>>(xh, Wqh, bq, ct,
        nullptr, ksum, nullptr, kvTg, yh, lw, lb, out, nullptr, nullptr);
}